// Round 5
// baseline (305.181 us; speedup 1.0000x reference)
//
#include <hip/hip_runtime.h>
#include <stdint.h>

typedef uint16_t u16;
typedef __attribute__((ext_vector_type(8))) short bf16x8;    // 8 bf16 (4 VGPRs)
typedef __attribute__((ext_vector_type(4))) float f32x4;     // MFMA C/D

#define EMB 768
#define NH 12
#define DK 64
#define BB 2
#define SS 2048
#define SCL 0.1803368801111244f   // 0.125 * log2(e)  (log2-domain scores)
#define M0  24.0f                 // fixed softmax offset (|tv| << 24+126 fp32 exp range)

// round-to-nearest-even f32 -> bf16 (scalar, cold paths)
__device__ __forceinline__ u16 f2bf(float x) {
  union { float f; uint32_t u; } v; v.f = x;
  uint32_t r = v.u + 0x7fffu + ((v.u >> 16) & 1u);
  return (u16)(r >> 16);
}

// gfx950 HW packed cvt: lo16 = bf16(a), hi16 = bf16(b), RNE
__device__ __forceinline__ uint32_t pk2(float a, float b) {
  uint32_t d;
  asm("v_cvt_pk_bf16_f32 %0, %1, %2" : "=v"(d) : "v"(a), "v"(b));
  return d;
}

__device__ __forceinline__ void gld16(const u16* g, u16* l) {
  __builtin_amdgcn_global_load_lds((const __attribute__((address_space(1))) void*)g,
                                   (__attribute__((address_space(3))) void*)l, 16, 0, 0);
}

// ---------------- pack kernels ----------------
// z<3: WqkvT[z][n][e] = Wz[h][e][d] (n=h*64+d);  z==3: WT[n][e] = W[e][n]
__global__ void pack_w(const float* __restrict__ wq, const float* __restrict__ wk,
                       const float* __restrict__ wv, const float* __restrict__ w,
                       u16* __restrict__ wqkvT, u16* __restrict__ wT) {
  const int z = blockIdx.y;
  int t = blockIdx.x * 256 + threadIdx.x;
  int n = t / EMB, e = t - n * EMB;
  if (z < 3) {
    const float* src = z == 0 ? wq : (z == 1 ? wk : wv);
    wqkvT[(size_t)z * EMB * EMB + t] = f2bf(src[((n >> 6) * EMB + e) * DK + (n & 63)]);
  } else {
    wT[t] = f2bf(w[e * EMB + n]);
  }
}

__global__ void pack_mask(const int* __restrict__ mask, uint32_t* __restrict__ bits) {
  size_t t = (size_t)blockIdx.x * 256 + threadIdx.x;
  int m = mask[t];
  unsigned long long ball = __ballot(m != 0);
  if ((threadIdx.x & 31) == 0)
    bits[t >> 5] = (uint32_t)((threadIdx.x & 32) ? (ball >> 32) : ball);
}

// ---------------- pipelined GEMM cores (C = A * Bt^T), 128x128 tile ----------------
#define GEMM_MFMA_BODY(Ab, Bb)                                                  \
    bf16x8 af[4], bfr[4];                                                       \
    _Pragma("unroll")                                                           \
    for (int i = 0; i < 4; ++i)                                                 \
      af[i] = *(const bf16x8*)((Ab) + (wr * 64 + i * 16 + c) * 32 + quad * 8);  \
    _Pragma("unroll")                                                           \
    for (int j = 0; j < 4; ++j)                                                 \
      bfr[j] = *(const bf16x8*)((Bb) + (wc * 64 + j * 16 + c) * 32 + quad * 8); \
    _Pragma("unroll")                                                           \
    for (int i = 0; i < 4; ++i)                                                 \
      _Pragma("unroll")                                                         \
      for (int j = 0; j < 4; ++j)                                               \
        acc[i][j] = __builtin_amdgcn_mfma_f32_16x16x32_bf16(af[i], bfr[j], acc[i][j], 0, 0, 0);

// A f32 in global (HW-pk cvt to bf16 while staging); Bt packed bf16 via gld16.
__device__ __forceinline__ void gemm_f32A_pipe(const float* __restrict__ A,
                                               const u16* __restrict__ Bt, int Kdim,
                                               int m0, int n0, u16* As, u16* Bs,
                                               f32x4 (&acc)[4][4]) {
  const int tid = threadIdx.x;
  const int lane = tid & 63, quad = lane >> 4, c = lane & 15;
  const int wr = (tid >> 6) >> 1, wc = (tid >> 6) & 1;
  float4 a0[2], a1[2];
#define LOAD_A(kk)                                                     \
  _Pragma("unroll")                                                    \
  for (int p = 0; p < 2; ++p) {                                        \
    int idx = (p * 256 + tid) * 8;                                     \
    const float* src = A + (size_t)(m0 + (idx >> 5)) * Kdim + (kk) + (idx & 31); \
    a0[p] = *(const float4*)src; a1[p] = *(const float4*)(src + 4);    \
  }
#define ISSUE_B(kk, buf)                                               \
  _Pragma("unroll")                                                    \
  for (int r = 0; r < 2; ++r) {                                        \
    int bo = r * 4096 + tid * 16;                                      \
    gld16(Bt + (size_t)(n0 + (bo >> 6)) * Kdim + (kk) + ((bo & 63) >> 1), \
          Bs + (buf) * 4096 + (bo >> 1));                              \
  }
  LOAD_A(0); ISSUE_B(0, 0);
  for (int kk = 0; kk < Kdim; kk += 32) {
    const int buf = (kk >> 5) & 1;
#pragma unroll
    for (int p = 0; p < 2; ++p) {                 // write A(kk) regs -> As[buf]
      int idx = (p * 256 + tid) * 8;
      uint4 pkv = { pk2(a0[p].x, a0[p].y), pk2(a0[p].z, a0[p].w),
                    pk2(a1[p].x, a1[p].y), pk2(a1[p].z, a1[p].w) };
      *(uint4*)(As + buf * 4096 + (idx >> 5) * 32 + (idx & 31)) = pkv;
    }
    __syncthreads();                              // drains B(kk) DMA + A writes
    if (kk + 32 < Kdim) { LOAD_A(kk + 32); ISSUE_B(kk + 32, buf ^ 1); }
    const u16* Ab = As + buf * 4096;
    const u16* Bb = Bs + buf * 4096;
    GEMM_MFMA_BODY(Ab, Bb)
  }
#undef LOAD_A
#undef ISSUE_B
}

__device__ __forceinline__ void gemm_bf16A_pipe(const u16* __restrict__ A,
                                                const u16* __restrict__ Bt, int Kdim,
                                                int m0, int n0, u16* As, u16* Bs,
                                                f32x4 (&acc)[4][4]) {
  const int tid = threadIdx.x;
  const int lane = tid & 63, quad = lane >> 4, c = lane & 15;
  const int wr = (tid >> 6) >> 1, wc = (tid >> 6) & 1;
#define ISSUE_AB(kk, buf)                                              \
  _Pragma("unroll")                                                    \
  for (int r = 0; r < 2; ++r) {                                        \
    int bo = r * 4096 + tid * 16;                                      \
    gld16(A  + (size_t)(m0 + (bo >> 6)) * Kdim + (kk) + ((bo & 63) >> 1), \
          As + (buf) * 4096 + (bo >> 1));                              \
    gld16(Bt + (size_t)(n0 + (bo >> 6)) * Kdim + (kk) + ((bo & 63) >> 1), \
          Bs + (buf) * 4096 + (bo >> 1));                              \
  }
  ISSUE_AB(0, 0);
  for (int kk = 0; kk < Kdim; kk += 32) {
    const int buf = (kk >> 5) & 1;
    __syncthreads();                              // drains DMA(kk)
    if (kk + 32 < Kdim) { ISSUE_AB(kk + 32, buf ^ 1); }
    const u16* Ab = As + buf * 4096;
    const u16* Bb = Bs + buf * 4096;
    GEMM_MFMA_BODY(Ab, Bb)
  }
#undef ISSUE_AB
}

// z=0: Q -> Qp[b,s,h*64+d]; z=1: K -> Kp same; z=2: V -> Vt[bh][d][t]
__launch_bounds__(256, 3)
__global__ void gemm_qkv(const float* __restrict__ q, const float* __restrict__ k,
                         const float* __restrict__ v, const u16* __restrict__ wt3,
                         u16* __restrict__ Qp, u16* __restrict__ Kp, u16* __restrict__ Vt) {
  __shared__ u16 As[2 * 128 * 32];
  __shared__ u16 Bs[2 * 128 * 32];
  const int z = blockIdx.z;
  const float* A = z == 0 ? q : (z == 1 ? k : v);
  const u16* Bt = wt3 + (size_t)z * EMB * EMB;
  const int m0 = blockIdx.y * 128, n0 = blockIdx.x * 128;
  f32x4 acc[4][4];
  const f32x4 fz = {0.f, 0.f, 0.f, 0.f};
#pragma unroll
  for (int i = 0; i < 4; ++i)
#pragma unroll
    for (int j = 0; j < 4; ++j) acc[i][j] = fz;
  gemm_f32A_pipe(A, Bt, EMB, m0, n0, As, Bs, acc);
  const int tid = threadIdx.x, lane = tid & 63, quad = lane >> 4, c = lane & 15;
  const int wr = (tid >> 6) >> 1, wc = (tid >> 6) & 1;
  if (z < 2) {
    u16* C = z == 0 ? Qp : Kp;
#pragma unroll
    for (int i = 0; i < 4; ++i)
#pragma unroll
      for (int j = 0; j < 4; ++j) {
        int row = m0 + wr * 64 + i * 16 + quad * 4;
        int col = n0 + wc * 64 + j * 16 + c;
#pragma unroll
        for (int r = 0; r < 4; r += 2) {
          uint32_t d = pk2(acc[i][j][r], acc[i][j][r + 1]);
          C[(size_t)(row + r) * EMB + col] = (u16)d;
          C[(size_t)(row + r + 1) * EMB + col] = (u16)(d >> 16);
        }
      }
  } else {
#pragma unroll
    for (int i = 0; i < 4; ++i)
#pragma unroll
      for (int j = 0; j < 4; ++j) {
        int row = m0 + wr * 64 + i * 16 + quad * 4;   // + r -> consecutive s
        int col = n0 + wc * 64 + j * 16 + c;          // n = h*64+d
        int b = row >> 11, s = row & 2047;
        int h = col >> 6, d = col & 63;
        uint2 pk = { pk2(acc[i][j][0], acc[i][j][1]), pk2(acc[i][j][2], acc[i][j][3]) };
        *(uint2*)(Vt + ((size_t)(b * NH + h) * DK + d) * SS + s) = pk;
      }
  }
}

__launch_bounds__(256, 3)
__global__ void gemm_out(const u16* __restrict__ A, const u16* __restrict__ Bt,
                         float* __restrict__ C) {
  __shared__ u16 As[2 * 128 * 32];
  __shared__ u16 Bs[2 * 128 * 32];
  const int m0 = blockIdx.y * 128, n0 = blockIdx.x * 128;
  f32x4 acc[4][4];
  const f32x4 fz = {0.f, 0.f, 0.f, 0.f};
#pragma unroll
  for (int i = 0; i < 4; ++i)
#pragma unroll
    for (int j = 0; j < 4; ++j) acc[i][j] = fz;
  gemm_bf16A_pipe(A, Bt, EMB, m0, n0, As, Bs, acc);
  const int tid = threadIdx.x, lane = tid & 63, quad = lane >> 4, c = lane & 15;
  const int wr = (tid >> 6) >> 1, wc = (tid >> 6) & 1;
#pragma unroll
  for (int i = 0; i < 4; ++i)
#pragma unroll
    for (int j = 0; j < 4; ++j)
#pragma unroll
      for (int r = 0; r < 4; ++r) {
        int row = m0 + wr * 64 + i * 16 + quad * 4 + r;
        int col = n0 + wc * 64 + j * 16 + c;
        C[(size_t)row * EMB + col] = acc[i][j][r];   // raw fp32
      }
}

// ---------------- flash attention v3 (fixed-offset softmax) ----------------
// grid (32, 24): x = 64-row Q tile, y = b*12+h. 4 waves, 16 rows/wave. Q in regs.
__launch_bounds__(256, 4)
__global__ void attn(const u16* __restrict__ Qp, const u16* __restrict__ Kp,
                     const u16* __restrict__ Vt, const uint32_t* __restrict__ mbits,
                     u16* __restrict__ AO) {
  __shared__ __align__(16) u16 KPs[128 * 72];   // K stride 72; P view stride 136 (aliased)
  __shared__ __align__(16) u16 Vs[64 * 136];    // V^T tile [d][t]
  __shared__ __align__(16) uint32_t Ms[256];    // mask tile: 64 rows x 4 words
  const int tid = threadIdx.x, wvi = tid >> 6, lane = tid & 63;
  const int quad = lane >> 4, c = lane & 15;
  const int bh = blockIdx.y, b = bh / NH, h = bh - b * NH;
  const int m0 = blockIdx.x * 64;
  const size_t qkbase = (size_t)b * SS * EMB + (size_t)h * DK;
  const size_t vtbase = (size_t)bh * DK * SS;
  const uint32_t* mrow = mbits + (size_t)b * SS * 64;

  // Q fragments in registers: rows m0 + wvi*16 + c, k = ks*32 + quad*8 + [0..7]
  bf16x8 aq[2];
  {
    const u16* qr = Qp + qkbase + (size_t)(m0 + wvi * 16 + c) * EMB + quad * 8;
#pragma unroll
    for (int ks = 0; ks < 2; ++ks) aq[ks] = *(const bf16x8*)(qr + ks * 32);
  }

  bf16x8 kreg[4], vreg[4];
  uint32_t mreg;
#define LOAD_TILE(t0)                                                            \
  _Pragma("unroll")                                                              \
  for (int p = 0; p < 4; ++p) {                                                  \
    int idx = (p * 256 + tid) * 8;                                               \
    kreg[p] = *(const bf16x8*)(Kp + qkbase + (size_t)((t0) + (idx >> 6)) * EMB + (idx & 63)); \
    vreg[p] = *(const bf16x8*)(Vt + vtbase + (size_t)(idx >> 7) * SS + (t0) + (idx & 127));  \
  }                                                                              \
  mreg = mrow[(size_t)(m0 + (tid >> 2)) * 64 + ((t0) >> 5) + (tid & 3)];

  LOAD_TILE(0)

  float lr[4] = {0.f, 0.f, 0.f, 0.f};    // per-lane partial sums (fixed-offset softmax)
  f32x4 o[4];
  const f32x4 fz = {0.f, 0.f, 0.f, 0.f};
#pragma unroll
  for (int n = 0; n < 4; ++n) o[n] = fz;

  for (int it = 0; it < 16; ++it) {
    const int t0 = it * 128;
    __syncthreads();                       // B0: prev-iter PV/Vs reads done
#pragma unroll
    for (int p = 0; p < 4; ++p) {          // stage tile t from regs
      int idx = (p * 256 + tid) * 8;
      *(bf16x8*)(KPs + (idx >> 6) * 72 + (idx & 63)) = kreg[p];
      *(bf16x8*)(Vs + (idx >> 7) * 136 + (idx & 127)) = vreg[p];
    }
    Ms[tid] = mreg;
    __syncthreads();                       // B1: staging visible
    if (it < 15) { LOAD_TILE(t0 + 128) }   // prefetch overlaps compute

    // S = Q K^T : 1 m-tile x 8 n-tiles x K=64
    f32x4 s[8];
#pragma unroll
    for (int j = 0; j < 8; ++j) s[j] = fz;
#pragma unroll
    for (int ks = 0; ks < 2; ++ks)
#pragma unroll
      for (int j = 0; j < 8; ++j) {
        bf16x8 bk = *(const bf16x8*)(KPs + (j * 16 + c) * 72 + ks * 32 + quad * 8);
        s[j] = __builtin_amdgcn_mfma_f32_16x16x32_bf16(aq[ks], bk, s[j], 0, 0, 0);
      }

    // fixed-offset softmax: p = mask ? exp2(s*SCL - M0) : 0.  No max tracking,
    // no cross-lane work, no o rescale — ratios exact after final 1/l.
    uint4 mw[4];
#pragma unroll
    for (int r = 0; r < 4; ++r)
      mw[r] = *(const uint4*)(Ms + (wvi * 16 + quad * 4 + r) * 4);
#pragma unroll
    for (int r = 0; r < 4; ++r) {
      uint32_t wsel[4] = {mw[r].x, mw[r].y, mw[r].z, mw[r].w};
      float ls = 0.f;
#pragma unroll
      for (int j = 0; j < 8; ++j) {
        float p = exp2f(fmaf(s[j][r], SCL, -M0));
        uint32_t bit = (wsel[j >> 1] >> ((j & 1) * 16 + c)) & 1u;
        p = bit ? p : 0.f;
        s[j][r] = p;
        ls += p;
      }
      lr[r] += ls;
    }
    __syncthreads();                       // B2: all QK reads of KPs done
    // write P (stride 136, aliases KPs), own rows only — HW pk cvt
#pragma unroll
    for (int r = 0; r < 4; ++r)
#pragma unroll
      for (int j = 0; j < 8; j += 2) {
        uint32_t d = pk2(s[j][r], s[j + 1][r]);
        u16* pw = KPs + (wvi * 16 + quad * 4 + r) * 136 + j * 16 + c;
        pw[0] = (u16)d;
        pw[16] = (u16)(d >> 16);
      }
    // O += P V (reads own-wave-written P rows: same-wave DS ordering)
#pragma unroll
    for (int ks = 0; ks < 4; ++ks) {
      bf16x8 ap = *(const bf16x8*)(KPs + (wvi * 16 + c) * 136 + ks * 32 + quad * 8);
#pragma unroll
      for (int n = 0; n < 4; ++n) {
        bf16x8 bv = *(const bf16x8*)(Vs + (n * 16 + c) * 136 + ks * 32 + quad * 8);
        o[n] = __builtin_amdgcn_mfma_f32_16x16x32_bf16(ap, bv, o[n], 0, 0, 0);
      }
    }
  }

#pragma unroll
  for (int r = 0; r < 4; ++r) {
    float ls = lr[r];
#pragma unroll
    for (int off = 1; off < 16; off <<= 1) ls += __shfl_xor(ls, off);
    float inv = 1.f / fmaxf(ls, 1e-20f);
    int srow = m0 + wvi * 16 + quad * 4 + r;
#pragma unroll
    for (int n = 0; n < 4; n += 2) {
      uint32_t d = pk2(o[n][r] * inv, o[n + 1][r] * inv);
      u16* ow = AO + qkbase + (size_t)srow * EMB + n * 16 + c;
      ow[0] = (u16)d;
      ow[16] = (u16)(d >> 16);
    }
  }
#undef LOAD_TILE
}

extern "C" void kernel_launch(void* const* d_in, const int* in_sizes, int n_in,
                              void* d_out, int out_size, void* d_ws, size_t ws_size,
                              hipStream_t stream) {
  const float* q  = (const float*)d_in[0];
  const float* k  = (const float*)d_in[1];
  const float* v  = (const float*)d_in[2];
  const int* mask = (const int*)d_in[3];
  const float* Wq = (const float*)d_in[4];
  const float* Wk = (const float*)d_in[5];
  const float* Wv = (const float*)d_in[6];
  const float* W  = (const float*)d_in[7];
  float* out = (float*)d_out;

  // d_out (12 MiB) as scratch for Kp + Vt, dead before gemm_out writes.
  u16* Kp = (u16*)d_out;                    // [b,s,h*64+d] bf16
  u16* Vt = (u16*)d_out + 3145728;          // [bh][d][t]   bf16

  // ws: 11.5 MiB
  u16* ws    = (u16*)d_ws;
  u16* Qp    = ws;                          // 3145728 u16; AO aliases
  u16* WqkvT = ws + 3145728;                // 1769472 u16
  u16* WT    = ws + 3145728 + 1769472;      // 589824 u16
  uint32_t* mb = (uint32_t*)(ws + 5505024); // 262144 u32
  u16* AO = Qp;

  pack_w<<<dim3(2304, 4), 256, 0, stream>>>(Wq, Wk, Wv, W, WqkvT, WT);
  pack_mask<<<dim3(32768), 256, 0, stream>>>(mask, mb);
  gemm_qkv<<<dim3(6, 32, 3), 256, 0, stream>>>(q, k, v, WqkvT, Qp, Kp, Vt);
  attn<<<dim3(32, 24), 256, 0, stream>>>(Qp, Kp, Vt, mb, AO);
  gemm_out<<<dim3(6, 32), 256, 0, stream>>>(AO, WT, out);
}

// Round 6
// 261.933 us; speedup vs baseline: 1.1651x; 1.1651x over previous
//
#include <hip/hip_runtime.h>
#include <stdint.h>

typedef uint16_t u16;
typedef __attribute__((ext_vector_type(8))) short bf16x8;    // 8 bf16 (4 VGPRs)
typedef __attribute__((ext_vector_type(4))) float f32x4;     // MFMA C/D

#define EMB 768
#define NH 12
#define DK 64
#define BB 2
#define SS 2048
#define SCL 0.1803368801111244f   // 0.125 * log2(e)  (log2-domain scores)
#define M0  24.0f                 // fixed softmax offset

// round-to-nearest-even f32 -> bf16 (scalar, cold paths)
__device__ __forceinline__ u16 f2bf(float x) {
  union { float f; uint32_t u; } v; v.f = x;
  uint32_t r = v.u + 0x7fffu + ((v.u >> 16) & 1u);
  return (u16)(r >> 16);
}

// gfx950 HW packed cvt: lo16 = bf16(a), hi16 = bf16(b), RNE
__device__ __forceinline__ uint32_t pk2(float a, float b) {
  uint32_t d;
  asm("v_cvt_pk_bf16_f32 %0, %1, %2" : "=v"(d) : "v"(a), "v"(b));
  return d;
}

__device__ __forceinline__ void gld16(const u16* g, u16* l) {
  __builtin_amdgcn_global_load_lds((const __attribute__((address_space(1))) void*)g,
                                   (__attribute__((address_space(3))) void*)l, 16, 0, 0);
}

// ---------------- pack kernels ----------------
// z<3: WqkvT[z][n][e] = Wz[h][e][d] (n=h*64+d);  z==3: WT[n][e] = W[e][n]
__global__ void pack_w(const float* __restrict__ wq, const float* __restrict__ wk,
                       const float* __restrict__ wv, const float* __restrict__ w,
                       u16* __restrict__ wqkvT, u16* __restrict__ wT) {
  const int z = blockIdx.y;
  int t = blockIdx.x * 256 + threadIdx.x;
  int n = t / EMB, e = t - n * EMB;
  if (z < 3) {
    const float* src = z == 0 ? wq : (z == 1 ? wk : wv);
    wqkvT[(size_t)z * EMB * EMB + t] = f2bf(src[((n >> 6) * EMB + e) * DK + (n & 63)]);
  } else {
    wT[t] = f2bf(w[e * EMB + n]);
  }
}

__global__ void pack_mask(const int* __restrict__ mask, uint32_t* __restrict__ bits) {
  size_t t = (size_t)blockIdx.x * 256 + threadIdx.x;
  int m = mask[t];
  unsigned long long ball = __ballot(m != 0);
  if ((threadIdx.x & 31) == 0)
    bits[t >> 5] = (uint32_t)((threadIdx.x & 32) ? (ball >> 32) : ball);
}

// ---------------- pipelined GEMM cores (C = A * Bt^T), 128x128 tile ----------------
#define GEMM_MFMA_BODY(Ab, Bb)                                                  \
    bf16x8 af[4], bfr[4];                                                       \
    _Pragma("unroll")                                                           \
    for (int i = 0; i < 4; ++i)                                                 \
      af[i] = *(const bf16x8*)((Ab) + (wr * 64 + i * 16 + c) * 32 + quad * 8);  \
    _Pragma("unroll")                                                           \
    for (int j = 0; j < 4; ++j)                                                 \
      bfr[j] = *(const bf16x8*)((Bb) + (wc * 64 + j * 16 + c) * 32 + quad * 8); \
    _Pragma("unroll")                                                           \
    for (int i = 0; i < 4; ++i)                                                 \
      _Pragma("unroll")                                                         \
      for (int j = 0; j < 4; ++j)                                               \
        acc[i][j] = __builtin_amdgcn_mfma_f32_16x16x32_bf16(af[i], bfr[j], acc[i][j], 0, 0, 0);

// A f32 in global (HW-pk cvt to bf16 while staging); Bt packed bf16 via gld16.
__device__ __forceinline__ void gemm_f32A_pipe(const float* __restrict__ A,
                                               const u16* __restrict__ Bt, int Kdim,
                                               int m0, int n0, u16* As, u16* Bs,
                                               f32x4 (&acc)[4][4]) {
  const int tid = threadIdx.x;
  const int lane = tid & 63, quad = lane >> 4, c = lane & 15;
  const int wr = (tid >> 6) >> 1, wc = (tid >> 6) & 1;
  float4 a0[2], a1[2];
#define LOAD_A(kk)                                                     \
  _Pragma("unroll")                                                    \
  for (int p = 0; p < 2; ++p) {                                        \
    int idx = (p * 256 + tid) * 8;                                     \
    const float* src = A + (size_t)(m0 + (idx >> 5)) * Kdim + (kk) + (idx & 31); \
    a0[p] = *(const float4*)src; a1[p] = *(const float4*)(src + 4);    \
  }
#define ISSUE_B(kk, buf)                                               \
  _Pragma("unroll")                                                    \
  for (int r = 0; r < 2; ++r) {                                        \
    int bo = r * 4096 + tid * 16;                                      \
    gld16(Bt + (size_t)(n0 + (bo >> 6)) * Kdim + (kk) + ((bo & 63) >> 1), \
          Bs + (buf) * 4096 + (bo >> 1));                              \
  }
  LOAD_A(0); ISSUE_B(0, 0);
  for (int kk = 0; kk < Kdim; kk += 32) {
    const int buf = (kk >> 5) & 1;
#pragma unroll
    for (int p = 0; p < 2; ++p) {                 // write A(kk) regs -> As[buf]
      int idx = (p * 256 + tid) * 8;
      uint4 pkv = { pk2(a0[p].x, a0[p].y), pk2(a0[p].z, a0[p].w),
                    pk2(a1[p].x, a1[p].y), pk2(a1[p].z, a1[p].w) };
      *(uint4*)(As + buf * 4096 + (idx >> 5) * 32 + (idx & 31)) = pkv;
    }
    __syncthreads();                              // drains B(kk) DMA + A writes
    if (kk + 32 < Kdim) { LOAD_A(kk + 32); ISSUE_B(kk + 32, buf ^ 1); }
    const u16* Ab = As + buf * 4096;
    const u16* Bb = Bs + buf * 4096;
    GEMM_MFMA_BODY(Ab, Bb)
  }
#undef LOAD_A
#undef ISSUE_B
}

__device__ __forceinline__ void gemm_bf16A_pipe(const u16* __restrict__ A,
                                                const u16* __restrict__ Bt, int Kdim,
                                                int m0, int n0, u16* As, u16* Bs,
                                                f32x4 (&acc)[4][4]) {
  const int tid = threadIdx.x;
  const int lane = tid & 63, quad = lane >> 4, c = lane & 15;
  const int wr = (tid >> 6) >> 1, wc = (tid >> 6) & 1;
#define ISSUE_AB(kk, buf)                                              \
  _Pragma("unroll")                                                    \
  for (int r = 0; r < 2; ++r) {                                        \
    int bo = r * 4096 + tid * 16;                                      \
    gld16(A  + (size_t)(m0 + (bo >> 6)) * Kdim + (kk) + ((bo & 63) >> 1), \
          As + (buf) * 4096 + (bo >> 1));                              \
    gld16(Bt + (size_t)(n0 + (bo >> 6)) * Kdim + (kk) + ((bo & 63) >> 1), \
          Bs + (buf) * 4096 + (bo >> 1));                              \
  }
  ISSUE_AB(0, 0);
  for (int kk = 0; kk < Kdim; kk += 32) {
    const int buf = (kk >> 5) & 1;
    __syncthreads();                              // drains DMA(kk)
    if (kk + 32 < Kdim) { ISSUE_AB(kk + 32, buf ^ 1); }
    const u16* Ab = As + buf * 4096;
    const u16* Bb = Bs + buf * 4096;
    GEMM_MFMA_BODY(Ab, Bb)
  }
#undef ISSUE_AB
}

// z=0: Q -> Qp[b,s,h*64+d]; z=1: K -> Kp same; z=2: V -> Vt[bh][d][t]
__launch_bounds__(256, 3)
__global__ void gemm_qkv(const float* __restrict__ q, const float* __restrict__ k,
                         const float* __restrict__ v, const u16* __restrict__ wt3,
                         u16* __restrict__ Qp, u16* __restrict__ Kp, u16* __restrict__ Vt) {
  __shared__ u16 As[2 * 128 * 32];
  __shared__ u16 Bs[2 * 128 * 32];
  const int z = blockIdx.z;
  const float* A = z == 0 ? q : (z == 1 ? k : v);
  const u16* Bt = wt3 + (size_t)z * EMB * EMB;
  const int m0 = blockIdx.y * 128, n0 = blockIdx.x * 128;
  f32x4 acc[4][4];
  const f32x4 fz = {0.f, 0.f, 0.f, 0.f};
#pragma unroll
  for (int i = 0; i < 4; ++i)
#pragma unroll
    for (int j = 0; j < 4; ++j) acc[i][j] = fz;
  gemm_f32A_pipe(A, Bt, EMB, m0, n0, As, Bs, acc);
  const int tid = threadIdx.x, lane = tid & 63, quad = lane >> 4, c = lane & 15;
  const int wr = (tid >> 6) >> 1, wc = (tid >> 6) & 1;
  if (z < 2) {
    u16* C = z == 0 ? Qp : Kp;
#pragma unroll
    for (int i = 0; i < 4; ++i)
#pragma unroll
      for (int j = 0; j < 4; ++j) {
        int row = m0 + wr * 64 + i * 16 + quad * 4;
        int col = n0 + wc * 64 + j * 16 + c;
#pragma unroll
        for (int r = 0; r < 4; r += 2) {
          uint32_t d = pk2(acc[i][j][r], acc[i][j][r + 1]);
          C[(size_t)(row + r) * EMB + col] = (u16)d;
          C[(size_t)(row + r + 1) * EMB + col] = (u16)(d >> 16);
        }
      }
  } else {
#pragma unroll
    for (int i = 0; i < 4; ++i)
#pragma unroll
      for (int j = 0; j < 4; ++j) {
        int row = m0 + wr * 64 + i * 16 + quad * 4;   // + r -> consecutive s
        int col = n0 + wc * 64 + j * 16 + c;          // n = h*64+d
        int b = row >> 11, s = row & 2047;
        int h = col >> 6, d = col & 63;
        uint2 pk = { pk2(acc[i][j][0], acc[i][j][1]), pk2(acc[i][j][2], acc[i][j][3]) };
        *(uint2*)(Vt + ((size_t)(b * NH + h) * DK + d) * SS + s) = pk;
      }
  }
}

__launch_bounds__(256, 3)
__global__ void gemm_out(const u16* __restrict__ A, const u16* __restrict__ Bt,
                         float* __restrict__ C) {
  __shared__ u16 As[2 * 128 * 32];
  __shared__ u16 Bs[2 * 128 * 32];
  const int m0 = blockIdx.y * 128, n0 = blockIdx.x * 128;
  f32x4 acc[4][4];
  const f32x4 fz = {0.f, 0.f, 0.f, 0.f};
#pragma unroll
  for (int i = 0; i < 4; ++i)
#pragma unroll
    for (int j = 0; j < 4; ++j) acc[i][j] = fz;
  gemm_bf16A_pipe(A, Bt, EMB, m0, n0, As, Bs, acc);
  const int tid = threadIdx.x, lane = tid & 63, quad = lane >> 4, c = lane & 15;
  const int wr = (tid >> 6) >> 1, wc = (tid >> 6) & 1;
#pragma unroll
  for (int i = 0; i < 4; ++i)
#pragma unroll
    for (int j = 0; j < 4; ++j)
#pragma unroll
      for (int r = 0; r < 4; ++r) {
        int row = m0 + wr * 64 + i * 16 + quad * 4 + r;
        int col = n0 + wc * 64 + j * 16 + c;
        C[(size_t)row * EMB + col] = acc[i][j][r];   // raw fp32
      }
}

// ---------------- flash attention v3b (fixed-offset softmax, no spills) ----------------
// grid (32, 24): x = 64-row Q tile, y = b*12+h. 4 waves, 16 rows/wave. Q in regs.
// launch_bounds(256,3): ~170 VGPR budget — round 5's (256,4) capped at 64 and spilled
// to scratch (WRITE_SIZE 6->59 MB). Do NOT tighten this again.
__launch_bounds__(256, 3)
__global__ void attn(const u16* __restrict__ Qp, const u16* __restrict__ Kp,
                     const u16* __restrict__ Vt, const uint32_t* __restrict__ mbits,
                     u16* __restrict__ AO) {
  __shared__ __align__(16) u16 KPs[128 * 72];   // K stride 72; P view stride 136 (aliased)
  __shared__ __align__(16) u16 Vs[64 * 136];    // V^T tile [d][t]
  __shared__ __align__(16) uint32_t Ms[256];    // mask tile: 64 rows x 4 words
  const int tid = threadIdx.x, wvi = tid >> 6, lane = tid & 63;
  const int quad = lane >> 4, c = lane & 15;
  const int bh = blockIdx.y, b = bh / NH, h = bh - b * NH;
  const int m0 = blockIdx.x * 64;
  const size_t qkbase = (size_t)b * SS * EMB + (size_t)h * DK;
  const size_t vtbase = (size_t)bh * DK * SS;
  const uint32_t* mrow = mbits + (size_t)b * SS * 64;

  // Q fragments in registers: rows m0 + wvi*16 + c, k = ks*32 + quad*8 + [0..7]
  bf16x8 aq[2];
  {
    const u16* qr = Qp + qkbase + (size_t)(m0 + wvi * 16 + c) * EMB + quad * 8;
#pragma unroll
    for (int ks = 0; ks < 2; ++ks) aq[ks] = *(const bf16x8*)(qr + ks * 32);
  }

  bf16x8 kreg[4], vreg[4];
  uint32_t mreg;
#define LOAD_TILE(t0)                                                            \
  _Pragma("unroll")                                                              \
  for (int p = 0; p < 4; ++p) {                                                  \
    int idx = (p * 256 + tid) * 8;                                               \
    kreg[p] = *(const bf16x8*)(Kp + qkbase + (size_t)((t0) + (idx >> 6)) * EMB + (idx & 63)); \
    vreg[p] = *(const bf16x8*)(Vt + vtbase + (size_t)(idx >> 7) * SS + (t0) + (idx & 127));  \
  }                                                                              \
  mreg = mrow[(size_t)(m0 + (tid >> 2)) * 64 + ((t0) >> 5) + (tid & 3)];

  LOAD_TILE(0)

  float lr[4] = {0.f, 0.f, 0.f, 0.f};    // per-lane partial sums (fixed-offset softmax)
  f32x4 o[4];
  const f32x4 fz = {0.f, 0.f, 0.f, 0.f};
#pragma unroll
  for (int n = 0; n < 4; ++n) o[n] = fz;

  for (int it = 0; it < 16; ++it) {
    const int t0 = it * 128;
    __syncthreads();                       // B0: prev-iter PV/Vs reads done
#pragma unroll
    for (int p = 0; p < 4; ++p) {          // stage tile t from regs
      int idx = (p * 256 + tid) * 8;
      *(bf16x8*)(KPs + (idx >> 6) * 72 + (idx & 63)) = kreg[p];
      *(bf16x8*)(Vs + (idx >> 7) * 136 + (idx & 127)) = vreg[p];
    }
    Ms[tid] = mreg;
    __syncthreads();                       // B1: staging visible
    if (it < 15) { LOAD_TILE(t0 + 128) }   // prefetch overlaps compute

    // S = Q K^T : 1 m-tile x 8 n-tiles x K=64
    f32x4 s[8];
#pragma unroll
    for (int j = 0; j < 8; ++j) s[j] = fz;
#pragma unroll
    for (int ks = 0; ks < 2; ++ks)
#pragma unroll
      for (int j = 0; j < 8; ++j) {
        bf16x8 bk = *(const bf16x8*)(KPs + (j * 16 + c) * 72 + ks * 32 + quad * 8);
        s[j] = __builtin_amdgcn_mfma_f32_16x16x32_bf16(aq[ks], bk, s[j], 0, 0, 0);
      }

    // fixed-offset softmax: p = mask ? exp2(s*SCL - M0) : 0.
#pragma unroll
    for (int r = 0; r < 4; ++r) {
      const uint4 mw = *(const uint4*)(Ms + (wvi * 16 + quad * 4 + r) * 4);
      uint32_t wsel[4] = {mw.x, mw.y, mw.z, mw.w};
      float ls = 0.f;
#pragma unroll
      for (int j = 0; j < 8; ++j) {
        float p = exp2f(fmaf(s[j][r], SCL, -M0));
        uint32_t bit = (wsel[j >> 1] >> ((j & 1) * 16 + c)) & 1u;
        p = bit ? p : 0.f;
        s[j][r] = p;
        ls += p;
      }
      lr[r] += ls;
    }
    __syncthreads();                       // B2: all QK reads of KPs done
    // write P (stride 136, aliases KPs), own rows only — HW pk cvt
#pragma unroll
    for (int r = 0; r < 4; ++r)
#pragma unroll
      for (int j = 0; j < 8; j += 2) {
        uint32_t d = pk2(s[j][r], s[j + 1][r]);
        u16* pw = KPs + (wvi * 16 + quad * 4 + r) * 136 + j * 16 + c;
        pw[0] = (u16)d;
        pw[16] = (u16)(d >> 16);
      }
    // O += P V (reads own-wave-written P rows: same-wave DS ordering)
#pragma unroll
    for (int ks = 0; ks < 4; ++ks) {
      bf16x8 ap = *(const bf16x8*)(KPs + (wvi * 16 + c) * 136 + ks * 32 + quad * 8);
#pragma unroll
      for (int n = 0; n < 4; ++n) {
        bf16x8 bv = *(const bf16x8*)(Vs + (n * 16 + c) * 136 + ks * 32 + quad * 8);
        o[n] = __builtin_amdgcn_mfma_f32_16x16x32_bf16(ap, bv, o[n], 0, 0, 0);
      }
    }
  }

#pragma unroll
  for (int r = 0; r < 4; ++r) {
    float ls = lr[r];
#pragma unroll
    for (int off = 1; off < 16; off <<= 1) ls += __shfl_xor(ls, off);
    float inv = 1.f / fmaxf(ls, 1e-20f);
    int srow = m0 + wvi * 16 + quad * 4 + r;
#pragma unroll
    for (int n = 0; n < 4; n += 2) {
      uint32_t d = pk2(o[n][r] * inv, o[n + 1][r] * inv);
      u16* ow = AO + qkbase + (size_t)srow * EMB + n * 16 + c;
      ow[0] = (u16)d;
      ow[16] = (u16)(d >> 16);
    }
  }
#undef LOAD_TILE
}

extern "C" void kernel_launch(void* const* d_in, const int* in_sizes, int n_in,
                              void* d_out, int out_size, void* d_ws, size_t ws_size,
                              hipStream_t stream) {
  const float* q  = (const float*)d_in[0];
  const float* k  = (const float*)d_in[1];
  const float* v  = (const float*)d_in[2];
  const int* mask = (const int*)d_in[3];
  const float* Wq = (const float*)d_in[4];
  const float* Wk = (const float*)d_in[5];
  const float* Wv = (const float*)d_in[6];
  const float* W  = (const float*)d_in[7];
  float* out = (float*)d_out;

  // d_out (12 MiB) as scratch for Kp + Vt, dead before gemm_out writes.
  u16* Kp = (u16*)d_out;                    // [b,s,h*64+d] bf16
  u16* Vt = (u16*)d_out + 3145728;          // [bh][d][t]   bf16

  // ws: 11.5 MiB
  u16* ws    = (u16*)d_ws;
  u16* Qp    = ws;                          // 3145728 u16; AO aliases
  u16* WqkvT = ws + 3145728;                // 1769472 u16
  u16* WT    = ws + 3145728 + 1769472;      // 589824 u16
  uint32_t* mb = (uint32_t*)(ws + 5505024); // 262144 u32
  u16* AO = Qp;

  pack_w<<<dim3(2304, 4), 256, 0, stream>>>(Wq, Wk, Wv, W, WqkvT, WT);
  pack_mask<<<dim3(32768), 256, 0, stream>>>(mask, mb);
  gemm_qkv<<<dim3(6, 32, 3), 256, 0, stream>>>(q, k, v, WqkvT, Qp, Kp, Vt);
  attn<<<dim3(32, 24), 256, 0, stream>>>(Qp, Kp, Vt, mb, AO);
  gemm_out<<<dim3(6, 32), 256, 0, stream>>>(AO, WT, out);
}

// Round 8
// 260.423 us; speedup vs baseline: 1.1719x; 1.0058x over previous
//
#include <hip/hip_runtime.h>
#include <stdint.h>

typedef uint16_t u16;
typedef __attribute__((ext_vector_type(8))) short bf16x8;    // 8 bf16 (4 VGPRs)
typedef __attribute__((ext_vector_type(4))) float f32x4;     // MFMA C/D

#define EMB 768
#define NH 12
#define DK 64
#define BB 2
#define SS 2048
#define SCL 0.1803368801111244f   // 0.125 * log2(e)  (log2-domain scores)
#define M0  24.0f                 // fixed softmax offset

// round-to-nearest-even f32 -> bf16 (scalar, cold paths)
__device__ __forceinline__ u16 f2bf(float x) {
  union { float f; uint32_t u; } v; v.f = x;
  uint32_t r = v.u + 0x7fffu + ((v.u >> 16) & 1u);
  return (u16)(r >> 16);
}

// gfx950 HW packed cvt: lo16 = bf16(a), hi16 = bf16(b), RNE
__device__ __forceinline__ uint32_t pk2(float a, float b) {
  uint32_t d;
  asm("v_cvt_pk_bf16_f32 %0, %1, %2" : "=v"(d) : "v"(a), "v"(b));
  return d;
}

__device__ __forceinline__ void gld16(const u16* g, u16* l) {
  __builtin_amdgcn_global_load_lds((const __attribute__((address_space(1))) void*)g,
                                   (__attribute__((address_space(3))) void*)l, 16, 0, 0);
}

// ---------------- fused pack kernel (weights + mask bits), one launch ----------------
__global__ void pack_all(const float* __restrict__ wq, const float* __restrict__ wk,
                         const float* __restrict__ wv, const float* __restrict__ w,
                         const int* __restrict__ mask,
                         u16* __restrict__ wqkvT, u16* __restrict__ wT,
                         uint32_t* __restrict__ bits) {
  uint32_t tl = blockIdx.x * 256 + threadIdx.x;
  const uint32_t WTOT = 4u * EMB * EMB;     // 2359296, multiple of 256
  if (tl < WTOT) {
    int z = tl / (EMB * EMB);
    int t = tl - z * (EMB * EMB);
    int n = t / EMB, e = t - n * EMB;
    if (z < 3) {
      const float* src = z == 0 ? wq : (z == 1 ? wk : wv);
      wqkvT[(size_t)z * EMB * EMB + t] = f2bf(src[((n >> 6) * EMB + e) * DK + (n & 63)]);
    } else {
      wT[t] = f2bf(w[e * EMB + n]);
    }
  } else {
    uint32_t mi = tl - WTOT;                // aligned: mi % 256 == threadIdx.x % 256
    int m = mask[mi];
    unsigned long long ball = __ballot(m != 0);
    if ((threadIdx.x & 31) == 0)
      bits[mi >> 5] = (uint32_t)((threadIdx.x & 32) ? (ball >> 32) : ball);
  }
}

// ---------------- pipelined GEMM cores (C = A * Bt^T), 128x128 tile ----------------
#define GEMM_MFMA_BODY(Ab, Bb)                                                  \
    bf16x8 af[4], bfr[4];                                                       \
    _Pragma("unroll")                                                           \
    for (int i = 0; i < 4; ++i)                                                 \
      af[i] = *(const bf16x8*)((Ab) + (wr * 64 + i * 16 + c) * 32 + quad * 8);  \
    _Pragma("unroll")                                                           \
    for (int j = 0; j < 4; ++j)                                                 \
      bfr[j] = *(const bf16x8*)((Bb) + (wc * 64 + j * 16 + c) * 32 + quad * 8); \
    _Pragma("unroll")                                                           \
    for (int i = 0; i < 4; ++i)                                                 \
      _Pragma("unroll")                                                         \
      for (int j = 0; j < 4; ++j)                                               \
        acc[i][j] = __builtin_amdgcn_mfma_f32_16x16x32_bf16(af[i], bfr[j], acc[i][j], 0, 0, 0);

// A f32 in global (HW-pk cvt to bf16 while staging); Bt packed bf16 via gld16.
__device__ __forceinline__ void gemm_f32A_pipe(const float* __restrict__ A,
                                               const u16* __restrict__ Bt, int Kdim,
                                               int m0, int n0, u16* As, u16* Bs,
                                               f32x4 (&acc)[4][4]) {
  const int tid = threadIdx.x;
  const int lane = tid & 63, quad = lane >> 4, c = lane & 15;
  const int wr = (tid >> 6) >> 1, wc = (tid >> 6) & 1;
  float4 a0[2], a1[2];
#define LOAD_A(kk)                                                     \
  _Pragma("unroll")                                                    \
  for (int p = 0; p < 2; ++p) {                                        \
    int idx = (p * 256 + tid) * 8;                                     \
    const float* src = A + (size_t)(m0 + (idx >> 5)) * Kdim + (kk) + (idx & 31); \
    a0[p] = *(const float4*)src; a1[p] = *(const float4*)(src + 4);    \
  }
#define ISSUE_B(kk, buf)                                               \
  _Pragma("unroll")                                                    \
  for (int r = 0; r < 2; ++r) {                                        \
    int bo = r * 4096 + tid * 16;                                      \
    gld16(Bt + (size_t)(n0 + (bo >> 6)) * Kdim + (kk) + ((bo & 63) >> 1), \
          Bs + (buf) * 4096 + (bo >> 1));                              \
  }
  LOAD_A(0); ISSUE_B(0, 0);
  for (int kk = 0; kk < Kdim; kk += 32) {
    const int buf = (kk >> 5) & 1;
#pragma unroll
    for (int p = 0; p < 2; ++p) {                 // write A(kk) regs -> As[buf]
      int idx = (p * 256 + tid) * 8;
      uint4 pkv = { pk2(a0[p].x, a0[p].y), pk2(a0[p].z, a0[p].w),
                    pk2(a1[p].x, a1[p].y), pk2(a1[p].z, a1[p].w) };
      *(uint4*)(As + buf * 4096 + (idx >> 5) * 32 + (idx & 31)) = pkv;
    }
    __syncthreads();                              // drains B(kk) DMA + A writes
    if (kk + 32 < Kdim) { LOAD_A(kk + 32); ISSUE_B(kk + 32, buf ^ 1); }
    const u16* Ab = As + buf * 4096;
    const u16* Bb = Bs + buf * 4096;
    GEMM_MFMA_BODY(Ab, Bb)
  }
#undef LOAD_A
#undef ISSUE_B
}

__device__ __forceinline__ void gemm_bf16A_pipe(const u16* __restrict__ A,
                                                const u16* __restrict__ Bt, int Kdim,
                                                int m0, int n0, u16* As, u16* Bs,
                                                f32x4 (&acc)[4][4]) {
  const int tid = threadIdx.x;
  const int lane = tid & 63, quad = lane >> 4, c = lane & 15;
  const int wr = (tid >> 6) >> 1, wc = (tid >> 6) & 1;
#define ISSUE_AB(kk, buf)                                              \
  _Pragma("unroll")                                                    \
  for (int r = 0; r < 2; ++r) {                                        \
    int bo = r * 4096 + tid * 16;                                      \
    gld16(A  + (size_t)(m0 + (bo >> 6)) * Kdim + (kk) + ((bo & 63) >> 1), \
          As + (buf) * 4096 + (bo >> 1));                              \
    gld16(Bt + (size_t)(n0 + (bo >> 6)) * Kdim + (kk) + ((bo & 63) >> 1), \
          Bs + (buf) * 4096 + (bo >> 1));                              \
  }
  ISSUE_AB(0, 0);
  for (int kk = 0; kk < Kdim; kk += 32) {
    const int buf = (kk >> 5) & 1;
    __syncthreads();                              // drains DMA(kk)
    if (kk + 32 < Kdim) { ISSUE_AB(kk + 32, buf ^ 1); }
    const u16* Ab = As + buf * 4096;
    const u16* Bb = Bs + buf * 4096;
    GEMM_MFMA_BODY(Ab, Bb)
  }
#undef ISSUE_AB
}

// z=0: Q -> Qp[b,s,h*64+d]; z=1: K -> Kp same; z=2: V -> Vt[bh][d][t]
__launch_bounds__(256, 3)
__global__ void gemm_qkv(const float* __restrict__ q, const float* __restrict__ k,
                         const float* __restrict__ v, const u16* __restrict__ wt3,
                         u16* __restrict__ Qp, u16* __restrict__ Kp, u16* __restrict__ Vt) {
  __shared__ u16 As[2 * 128 * 32];
  __shared__ u16 Bs[2 * 128 * 32];
  const int z = blockIdx.z;
  const float* A = z == 0 ? q : (z == 1 ? k : v);
  const u16* Bt = wt3 + (size_t)z * EMB * EMB;
  const int m0 = blockIdx.y * 128, n0 = blockIdx.x * 128;
  f32x4 acc[4][4];
  const f32x4 fz = {0.f, 0.f, 0.f, 0.f};
#pragma unroll
  for (int i = 0; i < 4; ++i)
#pragma unroll
    for (int j = 0; j < 4; ++j) acc[i][j] = fz;
  gemm_f32A_pipe(A, Bt, EMB, m0, n0, As, Bs, acc);
  const int tid = threadIdx.x, lane = tid & 63, quad = lane >> 4, c = lane & 15;
  const int wr = (tid >> 6) >> 1, wc = (tid >> 6) & 1;
  if (z < 2) {
    u16* C = z == 0 ? Qp : Kp;
#pragma unroll
    for (int i = 0; i < 4; ++i)
#pragma unroll
      for (int j = 0; j < 4; ++j) {
        int row = m0 + wr * 64 + i * 16 + quad * 4;
        int col = n0 + wc * 64 + j * 16 + c;
#pragma unroll
        for (int r = 0; r < 4; r += 2) {
          uint32_t d = pk2(acc[i][j][r], acc[i][j][r + 1]);
          C[(size_t)(row + r) * EMB + col] = (u16)d;
          C[(size_t)(row + r + 1) * EMB + col] = (u16)(d >> 16);
        }
      }
  } else {
#pragma unroll
    for (int i = 0; i < 4; ++i)
#pragma unroll
      for (int j = 0; j < 4; ++j) {
        int row = m0 + wr * 64 + i * 16 + quad * 4;   // + r -> consecutive s
        int col = n0 + wc * 64 + j * 16 + c;          // n = h*64+d
        int b = row >> 11, s = row & 2047;
        int h = col >> 6, d = col & 63;
        uint2 pk = { pk2(acc[i][j][0], acc[i][j][1]), pk2(acc[i][j][2], acc[i][j][3]) };
        *(uint2*)(Vt + ((size_t)(b * NH + h) * DK + d) * SS + s) = pk;
      }
  }
}

__launch_bounds__(256, 3)
__global__ void gemm_out(const u16* __restrict__ A, const u16* __restrict__ Bt,
                         float* __restrict__ C) {
  __shared__ u16 As[2 * 128 * 32];
  __shared__ u16 Bs[2 * 128 * 32];
  const int m0 = blockIdx.y * 128, n0 = blockIdx.x * 128;
  f32x4 acc[4][4];
  const f32x4 fz = {0.f, 0.f, 0.f, 0.f};
#pragma unroll
  for (int i = 0; i < 4; ++i)
#pragma unroll
    for (int j = 0; j < 4; ++j) acc[i][j] = fz;
  gemm_bf16A_pipe(A, Bt, EMB, m0, n0, As, Bs, acc);
  const int tid = threadIdx.x, lane = tid & 63, quad = lane >> 4, c = lane & 15;
  const int wr = (tid >> 6) >> 1, wc = (tid >> 6) & 1;
#pragma unroll
  for (int i = 0; i < 4; ++i)
#pragma unroll
    for (int j = 0; j < 4; ++j)
#pragma unroll
      for (int r = 0; r < 4; ++r) {
        int row = m0 + wr * 64 + i * 16 + quad * 4 + r;
        int col = n0 + wc * 64 + j * 16 + c;
        C[(size_t)row * EMB + col] = acc[i][j][r];   // raw fp32
      }
}

// ---------------- flash attention v4b: t-tile 64, 1 barrier/iter ----------------
// grid (32, 24): x = 64-row Q tile, y = b*12+h. 4 waves, 16 rows/wave. Q in regs.
// Double-buffered K/V LDS; P in its own buffer (per-wave-private rows -> no barrier).
// P row stride MUST be >= 64 (round 7 used 40 -> OOB into Ms -> Inf/NaN). 72 here.
__launch_bounds__(256, 3)
__global__ void attn(const u16* __restrict__ Qp, const u16* __restrict__ Kp,
                     const u16* __restrict__ Vt, const uint32_t* __restrict__ mbits,
                     u16* __restrict__ AO) {
  __shared__ __align__(16) u16 Ks[2][64 * 72];   // K tile [t'][d], stride 72
  __shared__ __align__(16) u16 Vs[2][64 * 72];   // V^T tile [d][t'], stride 72
  __shared__ __align__(16) u16 Ps[64 * 72];      // P [qrow][t'], stride 72
  __shared__ __align__(16) uint32_t Ms[2][128];  // mask: 64 rows x 2 words
  const int tid = threadIdx.x, wvi = tid >> 6, lane = tid & 63;
  const int quad = lane >> 4, c = lane & 15;
  const int bh = blockIdx.y, b = bh / NH, h = bh - b * NH;
  const int m0 = blockIdx.x * 64;
  const size_t qkbase = (size_t)b * SS * EMB + (size_t)h * DK;
  const size_t vtbase = (size_t)bh * DK * SS;
  const uint32_t* mrow = mbits + (size_t)b * SS * 64;

  // Q fragments: rows m0 + wvi*16 + c, k = ks*32 + quad*8 + [0..7]
  bf16x8 aq[2];
  {
    const u16* qr = Qp + qkbase + (size_t)(m0 + wvi * 16 + c) * EMB + quad * 8;
    aq[0] = *(const bf16x8*)qr;
    aq[1] = *(const bf16x8*)(qr + 32);
  }

  bf16x8 kreg[2], vreg[2];
  uint32_t mreg = 0;
  const int srow8 = tid >> 3, scol8 = (tid & 7) * 8;   // staging coords
#define LOADT(t0)                                                                 \
  {                                                                               \
    const u16* kb = Kp + qkbase + (size_t)((t0) + srow8) * EMB + scol8;           \
    kreg[0] = *(const bf16x8*)kb;                                                 \
    kreg[1] = *(const bf16x8*)(kb + 32 * EMB);                                    \
    const u16* vb = Vt + vtbase + (size_t)srow8 * SS + (t0) + scol8;              \
    vreg[0] = *(const bf16x8*)vb;                                                 \
    vreg[1] = *(const bf16x8*)(vb + 32 * SS);                                     \
    if (tid < 128) mreg = mrow[(size_t)(m0 + (tid >> 1)) * 64 + ((t0) >> 5) + (tid & 1)]; \
  }

  LOADT(0)

  float lr[4] = {0.f, 0.f, 0.f, 0.f};
  f32x4 o[4];
  const f32x4 fz = {0.f, 0.f, 0.f, 0.f};
#pragma unroll
  for (int n = 0; n < 4; ++n) o[n] = fz;

  for (int it = 0; it < 32; ++it) {
    const int buf = it & 1;
    {  // stage tile it from regs (waits vmcnt on prev iter's loads)
      u16* kd = &Ks[buf][srow8 * 72 + scol8];
      *(bf16x8*)kd = kreg[0];
      *(bf16x8*)(kd + 32 * 72) = kreg[1];
      u16* vd = &Vs[buf][srow8 * 72 + scol8];
      *(bf16x8*)vd = vreg[0];
      *(bf16x8*)(vd + 32 * 72) = vreg[1];
      if (tid < 128) Ms[buf][tid] = mreg;
    }
    __syncthreads();                        // staging visible + prev compute done
    if (it < 31) LOADT((it + 1) * 64)       // prefetch overlaps compute

    // S = Q K^T : 1 m-tile x 4 n-tiles x K=64
    f32x4 s[4];
#pragma unroll
    for (int j = 0; j < 4; ++j) s[j] = fz;
#pragma unroll
    for (int ks = 0; ks < 2; ++ks)
#pragma unroll
      for (int j = 0; j < 4; ++j) {
        bf16x8 bk = *(const bf16x8*)(&Ks[buf][(j * 16 + c) * 72 + ks * 32 + quad * 8]);
        s[j] = __builtin_amdgcn_mfma_f32_16x16x32_bf16(aq[ks], bk, s[j], 0, 0, 0);
      }

    // fixed-offset softmax: p = mask ? exp2(s*SCL - M0) : 0
#pragma unroll
    for (int r = 0; r < 4; ++r) {
      const uint2 mw = *(const uint2*)(&Ms[buf][(wvi * 16 + quad * 4 + r) * 2]);
      float ls = 0.f;
#pragma unroll
      for (int j = 0; j < 4; ++j) {
        float p = exp2f(fmaf(s[j][r], SCL, -M0));
        uint32_t bit = (((j & 2) ? mw.y : mw.x) >> ((j & 1) * 16 + c)) & 1u;
        p = bit ? p : 0.f;
        s[j][r] = p;
        ls += p;
      }
      lr[r] += ls;
    }

    // write P (own rows, no barrier needed)
#pragma unroll
    for (int r = 0; r < 4; ++r) {
      u16* pw = &Ps[(wvi * 16 + quad * 4 + r) * 72 + c];
#pragma unroll
      for (int j = 0; j < 4; j += 2) {
        uint32_t d = pk2(s[j][r], s[j + 1][r]);
        pw[j * 16] = (u16)d;
        pw[j * 16 + 16] = (u16)(d >> 16);
      }
    }

    // O += P V (reads own-wave-written P rows; lgkmcnt ordering within wave)
#pragma unroll
    for (int ks = 0; ks < 2; ++ks) {
      bf16x8 ap = *(const bf16x8*)(&Ps[(wvi * 16 + c) * 72 + ks * 32 + quad * 8]);
#pragma unroll
      for (int n = 0; n < 4; ++n) {
        bf16x8 bv = *(const bf16x8*)(&Vs[buf][(n * 16 + c) * 72 + ks * 32 + quad * 8]);
        o[n] = __builtin_amdgcn_mfma_f32_16x16x32_bf16(ap, bv, o[n], 0, 0, 0);
      }
    }
  }
#undef LOADT

#pragma unroll
  for (int r = 0; r < 4; ++r) {
    float ls = lr[r];
#pragma unroll
    for (int off = 1; off < 16; off <<= 1) ls += __shfl_xor(ls, off);
    float inv = 1.f / fmaxf(ls, 1e-20f);
    int srow = m0 + wvi * 16 + quad * 4 + r;
#pragma unroll
    for (int n = 0; n < 4; n += 2) {
      uint32_t d = pk2(o[n][r] * inv, o[n + 1][r] * inv);
      u16* ow = AO + qkbase + (size_t)srow * EMB + n * 16 + c;
      ow[0] = (u16)d;
      ow[16] = (u16)(d >> 16);
    }
  }
}

extern "C" void kernel_launch(void* const* d_in, const int* in_sizes, int n_in,
                              void* d_out, int out_size, void* d_ws, size_t ws_size,
                              hipStream_t stream) {
  const float* q  = (const float*)d_in[0];
  const float* k  = (const float*)d_in[1];
  const float* v  = (const float*)d_in[2];
  const int* mask = (const int*)d_in[3];
  const float* Wq = (const float*)d_in[4];
  const float* Wk = (const float*)d_in[5];
  const float* Wv = (const float*)d_in[6];
  const float* W  = (const float*)d_in[7];
  float* out = (float*)d_out;

  // d_out (12 MiB) as scratch for Kp + Vt, dead before gemm_out writes.
  u16* Kp = (u16*)d_out;                    // [b,s,h*64+d] bf16
  u16* Vt = (u16*)d_out + 3145728;          // [bh][d][t]   bf16

  // ws: 11.5 MiB
  u16* ws    = (u16*)d_ws;
  u16* Qp    = ws;                          // 3145728 u16; AO aliases
  u16* WqkvT = ws + 3145728;                // 1769472 u16
  u16* WT    = ws + 3145728 + 1769472;      // 589824 u16
  uint32_t* mb = (uint32_t*)(ws + 5505024); // 262144 u32
  u16* AO = Qp;

  pack_all<<<dim3(41984), 256, 0, stream>>>(Wq, Wk, Wv, W, mask, WqkvT, WT, mb);
  gemm_qkv<<<dim3(6, 32, 3), 256, 0, stream>>>(q, k, v, WqkvT, Qp, Kp, Vt);
  attn<<<dim3(32, 24), 256, 0, stream>>>(Qp, Kp, Vt, mb, AO);
  gemm_out<<<dim3(6, 32), 256, 0, stream>>>(AO, WT, out);
}

// Round 9
// 255.073 us; speedup vs baseline: 1.1964x; 1.0210x over previous
//
#include <hip/hip_runtime.h>
#include <stdint.h>

typedef uint16_t u16;
typedef __attribute__((ext_vector_type(8))) short bf16x8;    // 8 bf16 (4 VGPRs)
typedef __attribute__((ext_vector_type(4))) float f32x4;     // MFMA C/D

#define EMB 768
#define NH 12
#define DK 64
#define BB 2
#define SS 2048
#define SCL 0.1803368801111244f   // 0.125 * log2(e)  (log2-domain scores)
#define M0  24.0f                 // fixed softmax offset

// round-to-nearest-even f32 -> bf16 (scalar, cold paths)
__device__ __forceinline__ u16 f2bf(float x) {
  union { float f; uint32_t u; } v; v.f = x;
  uint32_t r = v.u + 0x7fffu + ((v.u >> 16) & 1u);
  return (u16)(r >> 16);
}

// gfx950 HW packed cvt: lo16 = bf16(a), hi16 = bf16(b), RNE
__device__ __forceinline__ uint32_t pk2(float a, float b) {
  uint32_t d;
  asm("v_cvt_pk_bf16_f32 %0, %1, %2" : "=v"(d) : "v"(a), "v"(b));
  return d;
}

__device__ __forceinline__ void gld16(const u16* g, u16* l) {
  __builtin_amdgcn_global_load_lds((const __attribute__((address_space(1))) void*)g,
                                   (__attribute__((address_space(3))) void*)l, 16, 0, 0);
}

// ---------------- fused pack kernel (weights + mask bits), one launch ----------------
__global__ void pack_all(const float* __restrict__ wq, const float* __restrict__ wk,
                         const float* __restrict__ wv, const float* __restrict__ w,
                         const int* __restrict__ mask,
                         u16* __restrict__ wqkvT, u16* __restrict__ wT,
                         uint32_t* __restrict__ bits) {
  uint32_t tl = blockIdx.x * 256 + threadIdx.x;
  const uint32_t WTOT = 4u * EMB * EMB;     // 2359296, multiple of 256
  if (tl < WTOT) {
    int z = tl / (EMB * EMB);
    int t = tl - z * (EMB * EMB);
    int n = t / EMB, e = t - n * EMB;
    if (z < 3) {
      const float* src = z == 0 ? wq : (z == 1 ? wk : wv);
      wqkvT[(size_t)z * EMB * EMB + t] = f2bf(src[((n >> 6) * EMB + e) * DK + (n & 63)]);
    } else {
      wT[t] = f2bf(w[e * EMB + n]);
    }
  } else {
    uint32_t mi = tl - WTOT;                // aligned: mi % 256 == threadIdx.x % 256
    int m = mask[mi];
    unsigned long long ball = __ballot(m != 0);
    if ((threadIdx.x & 31) == 0)
      bits[mi >> 5] = (uint32_t)((threadIdx.x & 32) ? (ball >> 32) : ball);
  }
}

// ---------------- pipelined GEMM cores (C = A * Bt^T), 128x128 tile ----------------
#define GEMM_MFMA_BODY(Ab, Bb)                                                  \
    bf16x8 af[4], bfr[4];                                                       \
    _Pragma("unroll")                                                           \
    for (int i = 0; i < 4; ++i)                                                 \
      af[i] = *(const bf16x8*)((Ab) + (wr * 64 + i * 16 + c) * 32 + quad * 8);  \
    _Pragma("unroll")                                                           \
    for (int j = 0; j < 4; ++j)                                                 \
      bfr[j] = *(const bf16x8*)((Bb) + (wc * 64 + j * 16 + c) * 32 + quad * 8); \
    _Pragma("unroll")                                                           \
    for (int i = 0; i < 4; ++i)                                                 \
      _Pragma("unroll")                                                         \
      for (int j = 0; j < 4; ++j)                                               \
        acc[i][j] = __builtin_amdgcn_mfma_f32_16x16x32_bf16(af[i], bfr[j], acc[i][j], 0, 0, 0);

// A f32 in global (HW-pk cvt to bf16 while staging); Bt packed bf16 via gld16.
__device__ __forceinline__ void gemm_f32A_pipe(const float* __restrict__ A,
                                               const u16* __restrict__ Bt, int Kdim,
                                               int m0, int n0, u16* As, u16* Bs,
                                               f32x4 (&acc)[4][4]) {
  const int tid = threadIdx.x;
  const int lane = tid & 63, quad = lane >> 4, c = lane & 15;
  const int wr = (tid >> 6) >> 1, wc = (tid >> 6) & 1;
  float4 a0[2], a1[2];
#define LOAD_A(kk)                                                     \
  _Pragma("unroll")                                                    \
  for (int p = 0; p < 2; ++p) {                                        \
    int idx = (p * 256 + tid) * 8;                                     \
    const float* src = A + (size_t)(m0 + (idx >> 5)) * Kdim + (kk) + (idx & 31); \
    a0[p] = *(const float4*)src; a1[p] = *(const float4*)(src + 4);    \
  }
#define ISSUE_B(kk, buf)                                               \
  _Pragma("unroll")                                                    \
  for (int r = 0; r < 2; ++r) {                                        \
    int bo = r * 4096 + tid * 16;                                      \
    gld16(Bt + (size_t)(n0 + (bo >> 6)) * Kdim + (kk) + ((bo & 63) >> 1), \
          Bs + (buf) * 4096 + (bo >> 1));                              \
  }
  LOAD_A(0); ISSUE_B(0, 0);
  for (int kk = 0; kk < Kdim; kk += 32) {
    const int buf = (kk >> 5) & 1;
#pragma unroll
    for (int p = 0; p < 2; ++p) {                 // write A(kk) regs -> As[buf]
      int idx = (p * 256 + tid) * 8;
      uint4 pkv = { pk2(a0[p].x, a0[p].y), pk2(a0[p].z, a0[p].w),
                    pk2(a1[p].x, a1[p].y), pk2(a1[p].z, a1[p].w) };
      *(uint4*)(As + buf * 4096 + (idx >> 5) * 32 + (idx & 31)) = pkv;
    }
    __syncthreads();                              // drains B(kk) DMA + A writes
    if (kk + 32 < Kdim) { LOAD_A(kk + 32); ISSUE_B(kk + 32, buf ^ 1); }
    const u16* Ab = As + buf * 4096;
    const u16* Bb = Bs + buf * 4096;
    GEMM_MFMA_BODY(Ab, Bb)
  }
#undef LOAD_A
#undef ISSUE_B
}

__device__ __forceinline__ void gemm_bf16A_pipe(const u16* __restrict__ A,
                                                const u16* __restrict__ Bt, int Kdim,
                                                int m0, int n0, u16* As, u16* Bs,
                                                f32x4 (&acc)[4][4]) {
  const int tid = threadIdx.x;
  const int lane = tid & 63, quad = lane >> 4, c = lane & 15;
  const int wr = (tid >> 6) >> 1, wc = (tid >> 6) & 1;
#define ISSUE_AB(kk, buf)                                              \
  _Pragma("unroll")                                                    \
  for (int r = 0; r < 2; ++r) {                                        \
    int bo = r * 4096 + tid * 16;                                      \
    gld16(A  + (size_t)(m0 + (bo >> 6)) * Kdim + (kk) + ((bo & 63) >> 1), \
          As + (buf) * 4096 + (bo >> 1));                              \
    gld16(Bt + (size_t)(n0 + (bo >> 6)) * Kdim + (kk) + ((bo & 63) >> 1), \
          Bs + (buf) * 4096 + (bo >> 1));                              \
  }
  ISSUE_AB(0, 0);
  for (int kk = 0; kk < Kdim; kk += 32) {
    const int buf = (kk >> 5) & 1;
    __syncthreads();                              // drains DMA(kk)
    if (kk + 32 < Kdim) { ISSUE_AB(kk + 32, buf ^ 1); }
    const u16* Ab = As + buf * 4096;
    const u16* Bb = Bs + buf * 4096;
    GEMM_MFMA_BODY(Ab, Bb)
  }
#undef ISSUE_AB
}

// z=0: Q -> Qp[b,s,h*64+d]; z=1: K -> Kp same; z=2: V -> Vt[bh][d][t]
__launch_bounds__(256, 3)
__global__ void gemm_qkv(const float* __restrict__ q, const float* __restrict__ k,
                         const float* __restrict__ v, const u16* __restrict__ wt3,
                         u16* __restrict__ Qp, u16* __restrict__ Kp, u16* __restrict__ Vt) {
  __shared__ u16 As[2 * 128 * 32];
  __shared__ u16 Bs[2 * 128 * 32];
  const int z = blockIdx.z;
  const float* A = z == 0 ? q : (z == 1 ? k : v);
  const u16* Bt = wt3 + (size_t)z * EMB * EMB;
  const int m0 = blockIdx.y * 128, n0 = blockIdx.x * 128;
  f32x4 acc[4][4];
  const f32x4 fz = {0.f, 0.f, 0.f, 0.f};
#pragma unroll
  for (int i = 0; i < 4; ++i)
#pragma unroll
    for (int j = 0; j < 4; ++j) acc[i][j] = fz;
  gemm_f32A_pipe(A, Bt, EMB, m0, n0, As, Bs, acc);
  const int tid = threadIdx.x, lane = tid & 63, quad = lane >> 4, c = lane & 15;
  const int wr = (tid >> 6) >> 1, wc = (tid >> 6) & 1;
  if (z < 2) {
    u16* C = z == 0 ? Qp : Kp;
#pragma unroll
    for (int i = 0; i < 4; ++i)
#pragma unroll
      for (int j = 0; j < 4; ++j) {
        int row = m0 + wr * 64 + i * 16 + quad * 4;
        int col = n0 + wc * 64 + j * 16 + c;
#pragma unroll
        for (int r = 0; r < 4; r += 2) {
          uint32_t d = pk2(acc[i][j][r], acc[i][j][r + 1]);
          C[(size_t)(row + r) * EMB + col] = (u16)d;
          C[(size_t)(row + r + 1) * EMB + col] = (u16)(d >> 16);
        }
      }
  } else {
#pragma unroll
    for (int i = 0; i < 4; ++i)
#pragma unroll
      for (int j = 0; j < 4; ++j) {
        int row = m0 + wr * 64 + i * 16 + quad * 4;   // + r -> consecutive s
        int col = n0 + wc * 64 + j * 16 + c;          // n = h*64+d
        int b = row >> 11, s = row & 2047;
        int h = col >> 6, d = col & 63;
        uint2 pk = { pk2(acc[i][j][0], acc[i][j][1]), pk2(acc[i][j][2], acc[i][j][3]) };
        *(uint2*)(Vt + ((size_t)(b * NH + h) * DK + d) * SS + s) = pk;
      }
  }
}

__launch_bounds__(256, 3)
__global__ void gemm_out(const u16* __restrict__ A, const u16* __restrict__ Bt,
                         float* __restrict__ C) {
  __shared__ u16 As[2 * 128 * 32];
  __shared__ u16 Bs[2 * 128 * 32];
  const int m0 = blockIdx.y * 128, n0 = blockIdx.x * 128;
  f32x4 acc[4][4];
  const f32x4 fz = {0.f, 0.f, 0.f, 0.f};
#pragma unroll
  for (int i = 0; i < 4; ++i)
#pragma unroll
    for (int j = 0; j < 4; ++j) acc[i][j] = fz;
  gemm_bf16A_pipe(A, Bt, EMB, m0, n0, As, Bs, acc);
  const int tid = threadIdx.x, lane = tid & 63, quad = lane >> 4, c = lane & 15;
  const int wr = (tid >> 6) >> 1, wc = (tid >> 6) & 1;
#pragma unroll
  for (int i = 0; i < 4; ++i)
#pragma unroll
    for (int j = 0; j < 4; ++j)
#pragma unroll
      for (int r = 0; r < 4; ++r) {
        int row = m0 + wr * 64 + i * 16 + quad * 4 + r;
        int col = n0 + wc * 64 + j * 16 + c;
        C[(size_t)row * EMB + col] = acc[i][j][r];   // raw fp32
      }
}

// ---------------- flash attention v5: 512 threads, t-split waves ----------------
// grid (32, 24): x = 64-row Q tile, y = b*12+h. 8 waves: (wq = w&3) x (half = w>>2).
// Wave (wq,half) computes Q-rows wq*16+c against t-cols half*32+[0,32).
// 24 waves/CU (3 blocks x 8) vs v4's 12 — attacks the latency-bound stall.
// Partial (o, l) reduced across halves through dead LDS at the end.
__launch_bounds__(512, 6)
__global__ void attn(const u16* __restrict__ Qp, const u16* __restrict__ Kp,
                     const u16* __restrict__ Vt, const uint32_t* __restrict__ mbits,
                     u16* __restrict__ AO) {
  __shared__ __align__(16) u16 Ks[2][64 * 72];   // K tile [t'][d], stride 72
  __shared__ __align__(16) u16 Vs[2][64 * 72];   // V^T tile [d][t'], stride 72
  __shared__ __align__(16) u16 Ps[64 * 72];      // P [qrow][t'], stride 72
  __shared__ __align__(16) uint32_t Ms[2][128];  // mask: 64 rows x 2 words
  const int tid = threadIdx.x, lane = tid & 63;
  const int quad = lane >> 4, c = lane & 15;
  const int w = tid >> 6, wq = w & 3, half = w >> 2;
  const int bh = blockIdx.y, b = bh / NH, h = bh - b * NH;
  const int m0 = blockIdx.x * 64;
  const size_t qkbase = (size_t)b * SS * EMB + (size_t)h * DK;
  const size_t vtbase = (size_t)bh * DK * SS;
  const uint32_t* mrow = mbits + (size_t)b * SS * 64;

  // Q fragments: rows m0 + wq*16 + c, k = ks*32 + quad*8 + [0..7]
  bf16x8 aq[2];
  {
    const u16* qr = Qp + qkbase + (size_t)(m0 + wq * 16 + c) * EMB + quad * 8;
    aq[0] = *(const bf16x8*)qr;
    aq[1] = *(const bf16x8*)(qr + 32);
  }

  bf16x8 kreg, vreg;
  uint32_t mreg = 0;
  const int srow = tid >> 3, scol = (tid & 7) * 8;   // 512 thr x 8 elem = 64x64 tile
#define LOADT(t0)                                                                 \
  {                                                                               \
    kreg = *(const bf16x8*)(Kp + qkbase + (size_t)((t0) + srow) * EMB + scol);    \
    vreg = *(const bf16x8*)(Vt + vtbase + (size_t)srow * SS + (t0) + scol);       \
    if (tid < 128) mreg = mrow[(size_t)(m0 + (tid >> 1)) * 64 + ((t0) >> 5) + (tid & 1)]; \
  }

  LOADT(0)

  float lr[4] = {0.f, 0.f, 0.f, 0.f};   // per-lane partials over this wave's t-half
  f32x4 o[4];
  const f32x4 fz = {0.f, 0.f, 0.f, 0.f};
#pragma unroll
  for (int n = 0; n < 4; ++n) o[n] = fz;

  for (int it = 0; it < 32; ++it) {
    const int buf = it & 1;
    {  // stage tile it from regs (waits vmcnt on prev iter's loads)
      *(bf16x8*)(&Ks[buf][srow * 72 + scol]) = kreg;
      *(bf16x8*)(&Vs[buf][srow * 72 + scol]) = vreg;
      if (tid < 128) Ms[buf][tid] = mreg;
    }
    __syncthreads();                        // staging visible + prev compute done
    if (it < 31) LOADT((it + 1) * 64)       // prefetch overlaps compute

    // S = Q K^T : 16 rows x 32 t-cols (this wave's half), K=64
    f32x4 s[2];
    s[0] = fz; s[1] = fz;
#pragma unroll
    for (int ks = 0; ks < 2; ++ks)
#pragma unroll
      for (int j = 0; j < 2; ++j) {
        bf16x8 bk = *(const bf16x8*)(&Ks[buf][(half * 32 + j * 16 + c) * 72 + ks * 32 + quad * 8]);
        s[j] = __builtin_amdgcn_mfma_f32_16x16x32_bf16(aq[ks], bk, s[j], 0, 0, 0);
      }

    // fixed-offset softmax: p = mask ? exp2(s*SCL - M0) : 0
#pragma unroll
    for (int r = 0; r < 4; ++r) {
      const uint32_t mw = Ms[buf][(wq * 16 + quad * 4 + r) * 2 + half];
      float ls = 0.f;
#pragma unroll
      for (int j = 0; j < 2; ++j) {
        float p = exp2f(fmaf(s[j][r], SCL, -M0));
        uint32_t bit = (mw >> (j * 16 + c)) & 1u;
        p = bit ? p : 0.f;
        s[j][r] = p;
        ls += p;
      }
      lr[r] += ls;
    }

    // write P (own rows+cols: rows wq*16+*, cols half*32+[0,32))
#pragma unroll
    for (int r = 0; r < 4; ++r) {
      uint32_t d = pk2(s[0][r], s[1][r]);
      u16* pw = &Ps[(wq * 16 + quad * 4 + r) * 72 + half * 32 + c];
      pw[0] = (u16)d;
      pw[16] = (u16)(d >> 16);
    }

    // O += P V over this wave's 32 t' (reads only cells this wave wrote)
    {
      bf16x8 ap = *(const bf16x8*)(&Ps[(wq * 16 + c) * 72 + half * 32 + quad * 8]);
#pragma unroll
      for (int n = 0; n < 4; ++n) {
        bf16x8 bv = *(const bf16x8*)(&Vs[buf][(n * 16 + c) * 72 + half * 32 + quad * 8]);
        o[n] = __builtin_amdgcn_mfma_f32_16x16x32_bf16(ap, bv, o[n], 0, 0, 0);
      }
    }
  }
#undef LOADT

  // ---- cross-half reduction: half 1 -> LDS, half 0 adds & writes out ----
  // reduce lr over the 16 c-lanes first (row totals for rows wq*16+quad*4+r)
#pragma unroll
  for (int r = 0; r < 4; ++r) {
#pragma unroll
    for (int off = 1; off < 16; off <<= 1) lr[r] += __shfl_xor(lr[r], off);
  }
  __syncthreads();                          // all waves done with Ks/Vs/Ms
  float* Osf = (float*)&Ks[0][0];           // 64 x 68 f32 (17408 B <= 18432 B)
  float* Lrf = (float*)&Ms[0][0];           // 64 f32
  if (half == 1) {
#pragma unroll
    for (int n = 0; n < 4; ++n)
#pragma unroll
      for (int r = 0; r < 4; ++r)
        Osf[(wq * 16 + quad * 4 + r) * 68 + n * 16 + c] = o[n][r];
    if (c == 0)
#pragma unroll
      for (int r = 0; r < 4; ++r)
        Lrf[wq * 16 + quad * 4 + r] = lr[r];
  }
  __syncthreads();
  if (half == 0) {
#pragma unroll
    for (int r = 0; r < 4; ++r) {
      int row = wq * 16 + quad * 4 + r;
      float ltot = lr[r] + Lrf[row];
      float inv = 1.f / fmaxf(ltot, 1e-20f);
      int srow_g = m0 + row;
#pragma unroll
      for (int n = 0; n < 4; n += 2) {
        float o0 = (o[n][r] + Osf[row * 68 + n * 16 + c]) * inv;
        float o1 = (o[n + 1][r] + Osf[row * 68 + (n + 1) * 16 + c]) * inv;
        uint32_t d = pk2(o0, o1);
        u16* ow = AO + qkbase + (size_t)srow_g * EMB + n * 16 + c;
        ow[0] = (u16)d;
        ow[16] = (u16)(d >> 16);
      }
    }
  }
}

extern "C" void kernel_launch(void* const* d_in, const int* in_sizes, int n_in,
                              void* d_out, int out_size, void* d_ws, size_t ws_size,
                              hipStream_t stream) {
  const float* q  = (const float*)d_in[0];
  const float* k  = (const float*)d_in[1];
  const float* v  = (const float*)d_in[2];
  const int* mask = (const int*)d_in[3];
  const float* Wq = (const float*)d_in[4];
  const float* Wk = (const float*)d_in[5];
  const float* Wv = (const float*)d_in[6];
  const float* W  = (const float*)d_in[7];
  float* out = (float*)d_out;

  // d_out (12 MiB) as scratch for Kp + Vt, dead before gemm_out writes.
  u16* Kp = (u16*)d_out;                    // [b,s,h*64+d] bf16
  u16* Vt = (u16*)d_out + 3145728;          // [bh][d][t]   bf16

  // ws: 11.5 MiB
  u16* ws    = (u16*)d_ws;
  u16* Qp    = ws;                          // 3145728 u16; AO aliases
  u16* WqkvT = ws + 3145728;                // 1769472 u16
  u16* WT    = ws + 3145728 + 1769472;      // 589824 u16
  uint32_t* mb = (uint32_t*)(ws + 5505024); // 262144 u32
  u16* AO = Qp;

  pack_all<<<dim3(41984), 256, 0, stream>>>(Wq, Wk, Wv, W, mask, WqkvT, WT, mb);
  gemm_qkv<<<dim3(6, 32, 3), 256, 0, stream>>>(q, k, v, WqkvT, Qp, Kp, Vt);
  attn<<<dim3(32, 24), 512, 0, stream>>>(Qp, Kp, Vt, mb, AO);
  gemm_out<<<dim3(6, 32), 256, 0, stream>>>(AO, WT, out);
}